// Round 1
// baseline (544.046 us; speedup 1.0000x reference)
//
#include <hip/hip_runtime.h>
#include <float.h>

#define NN 50000
#define NE 800000
#define FD 64
#define NG 64

// ---------- degree ----------
__global__ void k_deg_init(float* __restrict__ deg) {
    int i = blockIdx.x * blockDim.x + threadIdx.x;
    if (i < NN) deg[i] = 1.0f;  // self loop
}

__global__ void k_deg_count(const int* __restrict__ dst, float* __restrict__ deg) {
    int i = blockIdx.x * blockDim.x + threadIdx.x;
    if (i < NE) atomicAdd(&deg[dst[i]], 1.0f);
}

__global__ void k_rsqrt(float* __restrict__ deg) {
    int i = blockIdx.x * blockDim.x + threadIdx.x;
    if (i < NN) deg[i] = rsqrtf(deg[i]);  // deg >= 1 always
}

// ---------- GEMM: H[N,64] = X[N,64] @ W[64,64] ----------
// one wave per row; x-row held one element per lane, broadcast via shfl;
// Ws[k*64+lane] -> stride-1 across lanes, 2 lanes/bank = conflict-free.
__global__ __launch_bounds__(256) void k_gemm64(const float* __restrict__ X,
                                                const float* __restrict__ W,
                                                float* __restrict__ H) {
    __shared__ float Ws[64 * 64];
    for (int i = threadIdx.x; i < 64 * 64; i += blockDim.x) Ws[i] = W[i];
    __syncthreads();
    int gtid  = blockIdx.x * blockDim.x + threadIdx.x;
    int wave  = gtid >> 6;
    int lane  = threadIdx.x & 63;
    int nwave = (gridDim.x * blockDim.x) >> 6;
    for (int r = wave; r < NN; r += nwave) {
        float xv  = X[r * FD + lane];
        float acc = 0.0f;
#pragma unroll
        for (int k = 0; k < 64; ++k) {
            float xk = __shfl(xv, k);
            acc = fmaf(xk, Ws[k * 64 + lane], acc);
        }
        H[r * FD + lane] = acc;
    }
}

// ---------- self-loop init: O = H * dis^2 ----------
__global__ void k_selfinit(const float* __restrict__ H, const float* __restrict__ dis,
                           float* __restrict__ O) {
    int t = blockIdx.x * blockDim.x + threadIdx.x;
    if (t < NN * FD) {
        int r  = t >> 6;
        float d = dis[r];
        O[t] = H[t] * d * d;
    }
}

// ---------- edge scatter: O[dst] += H[src] * dis[src]*dis[dst] ----------
__global__ __launch_bounds__(256) void k_scatter(const int* __restrict__ src,
                                                 const int* __restrict__ dst,
                                                 const float* __restrict__ dis,
                                                 const float* __restrict__ H,
                                                 float* __restrict__ O) {
    int gtid  = blockIdx.x * blockDim.x + threadIdx.x;
    int wave  = gtid >> 6;
    int lane  = threadIdx.x & 63;
    int nwave = (gridDim.x * blockDim.x) >> 6;
    for (int e = wave; e < NE; e += nwave) {
        int s = src[e];
        int d = dst[e];
        float nrm = dis[s] * dis[d];
        float v = H[s * FD + lane] * nrm;
        atomicAdd(&O[d * FD + lane], v);
    }
}

// ---------- bias + relu ----------
__global__ void k_bias_relu(float* __restrict__ O, const float* __restrict__ b) {
    int t = blockIdx.x * blockDim.x + threadIdx.x;
    if (t < NN * FD) {
        float v = O[t] + b[t & 63];
        O[t] = fmaxf(v, 0.0f);
    }
}

// ---------- monotonic float<->uint encoding for atomic max ----------
__device__ inline unsigned encf(float f) {
    unsigned u = __float_as_uint(f);
    return (u & 0x80000000u) ? ~u : (u | 0x80000000u);
}
__device__ inline float decf(unsigned e) {
    unsigned u = (e & 0x80000000u) ? (e ^ 0x80000000u) : ~e;
    return __uint_as_float(u);
}

__global__ void k_gmax_init(unsigned* __restrict__ gmax) {
    int i = blockIdx.x * blockDim.x + threadIdx.x;
    if (i < NG * FD) gmax[i] = encf(-FLT_MAX);
}

// layer-2 finalize: v = O + b2, then per-graph atomic max (no store of O needed)
__global__ __launch_bounds__(256) void k_bias_gmax(const float* __restrict__ O,
                                                   const float* __restrict__ b,
                                                   const int* __restrict__ batch,
                                                   unsigned* __restrict__ gmax) {
    int gtid  = blockIdx.x * blockDim.x + threadIdx.x;
    int wave  = gtid >> 6;
    int lane  = threadIdx.x & 63;
    int nwave = (gridDim.x * blockDim.x) >> 6;
    for (int r = wave; r < NN; r += nwave) {
        float v = O[r * FD + lane] + b[lane];
        atomicMax(&gmax[batch[r] * FD + lane], encf(v));
    }
}

// ---------- final: out[g,c] = sum_f gmax[g,f] * Wlin[f,c] + blin[c] ----------
__global__ __launch_bounds__(128) void k_final(const unsigned* __restrict__ gmax,
                                               const float* __restrict__ Wlin,
                                               const float* __restrict__ blin,
                                               float* __restrict__ out) {
    __shared__ float G[NG * FD];
    for (int i = threadIdx.x; i < NG * FD; i += 128) G[i] = decf(gmax[i]);
    __syncthreads();
    int t = threadIdx.x;          // 0..127
    int g = t >> 1, c = t & 1;
    float acc = blin[c];
#pragma unroll
    for (int f = 0; f < 64; ++f) acc = fmaf(G[g * 64 + f], Wlin[f * 2 + c], acc);
    out[g * 2 + c] = acc;
}

extern "C" void kernel_launch(void* const* d_in, const int* in_sizes, int n_in,
                              void* d_out, int out_size, void* d_ws, size_t ws_size,
                              hipStream_t stream) {
    const float* x     = (const float*)d_in[0];
    const int*   eidx  = (const int*)d_in[1];
    const int*   batch = (const int*)d_in[2];
    const float* W1    = (const float*)d_in[3];
    const float* b1    = (const float*)d_in[4];
    const float* W2    = (const float*)d_in[5];
    const float* b2    = (const float*)d_in[6];
    const float* Wlin  = (const float*)d_in[7];
    const float* blin  = (const float*)d_in[8];
    float* out = (float*)d_out;

    const int* src = eidx;
    const int* dst = eidx + NE;

    // workspace layout (bytes, 256-aligned)
    char* ws = (char*)d_ws;
    float*    deg  = (float*)(ws + 0);                 // NN floats
    float*    H    = (float*)(ws + 200704);            // NN*64 floats (12.8 MB)
    float*    O    = (float*)(ws + 200704 + 12800000); // NN*64 floats (12.8 MB)
    unsigned* gmax = (unsigned*)(ws + 200704 + 2 * 12800000); // 4096 u32

    const int B = 256;
    const int gN   = (NN + B - 1) / B;        // node-count grid
    const int gE   = (NE + B - 1) / B;        // edge-count grid
    const int gNF  = (NN * FD + B - 1) / B;   // elementwise grid
    const int gemmBlocks = 1024;              // 4096 waves, ~12 rows each
    const int scatBlocks = 2048;              // 8192 waves, ~98 edges each

    // degrees + norm
    k_deg_init<<<gN, B, 0, stream>>>(deg);
    k_deg_count<<<gE, B, 0, stream>>>(dst, deg);
    k_rsqrt<<<gN, B, 0, stream>>>(deg);       // deg now holds dis = rsqrt(deg)

    // ---- layer 1 ----
    k_gemm64<<<gemmBlocks, B, 0, stream>>>(x, W1, H);
    k_selfinit<<<gNF, B, 0, stream>>>(H, deg, O);
    k_scatter<<<scatBlocks, B, 0, stream>>>(src, dst, deg, H, O);
    k_bias_relu<<<gNF, B, 0, stream>>>(O, b1);

    // ---- layer 2 (H buffer reused for transformed features) ----
    k_gemm64<<<gemmBlocks, B, 0, stream>>>(O, W2, H);
    k_selfinit<<<gNF, B, 0, stream>>>(H, deg, O);
    k_scatter<<<scatBlocks, B, 0, stream>>>(src, dst, deg, H, O);

    // ---- pooling + head ----
    k_gmax_init<<<(NG * FD + B - 1) / B, B, 0, stream>>>(gmax);
    k_bias_gmax<<<scatBlocks, B, 0, stream>>>(O, b2, batch, gmax);
    k_final<<<1, 128, 0, stream>>>(gmax, Wlin, blin, out);
}

// Round 2
// 289.685 us; speedup vs baseline: 1.8781x; 1.8781x over previous
//
#include <hip/hip_runtime.h>
#include <float.h>

#define NN 50000
#define NE 800000
#define FD 64
#define NG 64
#define SCAN_B 256
#define NBLK ((NN + SCAN_B - 1) / SCAN_B)   // 196

// ---------- degree / norm ----------
__global__ void k_cnt_init(int* __restrict__ cnt) {
    int i = blockIdx.x * blockDim.x + threadIdx.x;
    if (i < NN) cnt[i] = 0;
}

__global__ void k_cnt(const int* __restrict__ dst, int* __restrict__ cnt) {
    int i = blockIdx.x * blockDim.x + threadIdx.x;
    if (i < NE) atomicAdd(&cnt[dst[i]], 1);
}

__global__ void k_dis(const int* __restrict__ cnt, float* __restrict__ dis) {
    int i = blockIdx.x * blockDim.x + threadIdx.x;
    if (i < NN) dis[i] = rsqrtf((float)cnt[i] + 1.0f);  // +1 = self loop
}

// ---------- exclusive scan of cnt -> rp (CSR row pointers) ----------
__global__ void k_scan1(const int* __restrict__ cnt, int* __restrict__ rp,
                        int* __restrict__ bsum) {
    __shared__ int tmp[SCAN_B];
    int b = blockIdx.x, t = threadIdx.x;
    int i = b * SCAN_B + t;
    int v = (i < NN) ? cnt[i] : 0;
    tmp[t] = v;
    __syncthreads();
    for (int off = 1; off < SCAN_B; off <<= 1) {
        int add = (t >= off) ? tmp[t - off] : 0;
        __syncthreads();
        tmp[t] += add;
        __syncthreads();
    }
    if (i < NN) rp[i] = tmp[t] - v;           // exclusive within block
    if (t == SCAN_B - 1) bsum[b] = tmp[t];    // block total
}

__global__ void k_scan2(int* __restrict__ bsum) {
    __shared__ int tmp[256];
    int t = threadIdx.x;
    int v = (t < NBLK) ? bsum[t] : 0;
    tmp[t] = v;
    __syncthreads();
    for (int off = 1; off < 256; off <<= 1) {
        int add = (t >= off) ? tmp[t - off] : 0;
        __syncthreads();
        tmp[t] += add;
        __syncthreads();
    }
    if (t < NBLK) bsum[t] = tmp[t] - v;       // exclusive
}

__global__ void k_scan3(int* __restrict__ rp, const int* __restrict__ bsum,
                        int* __restrict__ cnt) {
    int i = blockIdx.x * blockDim.x + threadIdx.x;
    if (i < NN) {
        rp[i] += bsum[i / SCAN_B];
        cnt[i] = 0;                           // becomes fill cursor
    }
    if (i == 0) rp[NN] = NE;
}

// ---------- CSR fill: esrc[pos] = src, grouped by dst ----------
__global__ void k_fill(const int* __restrict__ src, const int* __restrict__ dst,
                       const int* __restrict__ rp, int* __restrict__ cur,
                       int* __restrict__ esrc) {
    int e = blockIdx.x * blockDim.x + threadIdx.x;
    if (e < NE) {
        int d = dst[e];
        int p = rp[d] + atomicAdd(&cur[d], 1);
        esrc[p] = src[e];
    }
}

// ---------- GEMM: H[N,64] = X[N,64] @ W[64,64] ----------
__global__ __launch_bounds__(256) void k_gemm64(const float* __restrict__ X,
                                                const float* __restrict__ W,
                                                float* __restrict__ H) {
    __shared__ float Ws[64 * 64];
    for (int i = threadIdx.x; i < 64 * 64; i += blockDim.x) Ws[i] = W[i];
    __syncthreads();
    int gtid  = blockIdx.x * blockDim.x + threadIdx.x;
    int wave  = gtid >> 6;
    int lane  = threadIdx.x & 63;
    int nwave = (gridDim.x * blockDim.x) >> 6;
    for (int r = wave; r < NN; r += nwave) {
        float xv  = X[r * FD + lane];
        float acc = 0.0f;
#pragma unroll
        for (int k = 0; k < 64; ++k) {
            float xk = __shfl(xv, k);
            acc = fmaf(xk, Ws[k * 64 + lane], acc);
        }
        H[r * FD + lane] = acc;
    }
}

// ---------- monotonic float<->uint encoding for atomic max ----------
__device__ inline unsigned encf(float f) {
    unsigned u = __float_as_uint(f);
    return (u & 0x80000000u) ? ~u : (u | 0x80000000u);
}
__device__ inline float decf(unsigned e) {
    unsigned u = (e & 0x80000000u) ? (e ^ 0x80000000u) : ~e;
    return __uint_as_float(u);
}

__global__ void k_gmax_init(unsigned* __restrict__ gmax) {
    int i = blockIdx.x * blockDim.x + threadIdx.x;
    if (i < NG * FD) gmax[i] = encf(-FLT_MAX);
}

// ---------- gather aggregation: one wave per dst node, lane = feature ----------
// out_row = dis[d] * ( sum_s dis[s]*H[s,:] + dis[d]*H[d,:] ) + bias
// mode 0: O[d] = relu(out_row)     mode 1: atomicMax(gmax[batch[d]], out_row)
__global__ __launch_bounds__(256) void k_gather(const int* __restrict__ rp,
                                                const int* __restrict__ esrc,
                                                const float* __restrict__ dis,
                                                const float* __restrict__ H,
                                                const float* __restrict__ bias,
                                                float* __restrict__ O,
                                                const int* __restrict__ batch,
                                                unsigned* __restrict__ gmax,
                                                int mode) {
    int gtid  = blockIdx.x * blockDim.x + threadIdx.x;
    int wave  = gtid >> 6;
    int lane  = threadIdx.x & 63;
    int nwave = (gridDim.x * blockDim.x) >> 6;
    for (int d = wave; d < NN; d += nwave) {
        int beg = rp[d], end = rp[d + 1];
        float dd = dis[d];
        float a0 = dd * H[d * FD + lane];   // self-loop term
        float a1 = 0.f, a2 = 0.f, a3 = 0.f;
        int j = beg;
        for (; j + 4 <= end; j += 4) {
            int s0 = esrc[j], s1 = esrc[j + 1], s2 = esrc[j + 2], s3 = esrc[j + 3];
            float w0 = dis[s0], w1 = dis[s1], w2 = dis[s2], w3 = dis[s3];
            a0 = fmaf(w0, H[s0 * FD + lane], a0);
            a1 = fmaf(w1, H[s1 * FD + lane], a1);
            a2 = fmaf(w2, H[s2 * FD + lane], a2);
            a3 = fmaf(w3, H[s3 * FD + lane], a3);
        }
        for (; j < end; ++j) {
            int s = esrc[j];
            a0 = fmaf(dis[s], H[s * FD + lane], a0);
        }
        float v = dd * ((a0 + a1) + (a2 + a3)) + bias[lane];
        if (mode == 0) {
            O[d * FD + lane] = fmaxf(v, 0.0f);
        } else {
            atomicMax(&gmax[batch[d] * FD + lane], encf(v));
        }
    }
}

// ---------- final: out[g,c] = sum_f gmax[g,f] * Wlin[f,c] + blin[c] ----------
__global__ __launch_bounds__(128) void k_final(const unsigned* __restrict__ gmax,
                                               const float* __restrict__ Wlin,
                                               const float* __restrict__ blin,
                                               float* __restrict__ out) {
    __shared__ float G[NG * FD];
    for (int i = threadIdx.x; i < NG * FD; i += 128) G[i] = decf(gmax[i]);
    __syncthreads();
    int t = threadIdx.x;
    int g = t >> 1, c = t & 1;
    float acc = blin[c];
#pragma unroll
    for (int f = 0; f < 64; ++f) acc = fmaf(G[g * 64 + f], Wlin[f * 2 + c], acc);
    out[g * 2 + c] = acc;
}

extern "C" void kernel_launch(void* const* d_in, const int* in_sizes, int n_in,
                              void* d_out, int out_size, void* d_ws, size_t ws_size,
                              hipStream_t stream) {
    const float* x     = (const float*)d_in[0];
    const int*   eidx  = (const int*)d_in[1];
    const int*   batch = (const int*)d_in[2];
    const float* W1    = (const float*)d_in[3];
    const float* b1    = (const float*)d_in[4];
    const float* W2    = (const float*)d_in[5];
    const float* b2    = (const float*)d_in[6];
    const float* Wlin  = (const float*)d_in[7];
    const float* blin  = (const float*)d_in[8];
    float* out = (float*)d_out;

    const int* src = eidx;
    const int* dst = eidx + NE;

    // workspace layout (bytes, aligned)
    char* ws = (char*)d_ws;
    size_t off = 0;
    auto alloc = [&](size_t bytes) { char* p = ws + off; off += (bytes + 255) & ~size_t(255); return p; };
    int*      cnt  = (int*)alloc(NN * 4);            // histogram, then fill cursor
    float*    dis  = (float*)alloc(NN * 4);
    int*      rp   = (int*)alloc((NN + 1) * 4);
    int*      bsum = (int*)alloc(NBLK * 4);
    int*      esrc = (int*)alloc(NE * 4);            // 3.2 MB
    unsigned* gmax = (unsigned*)alloc(NG * FD * 4);
    float*    H    = (float*)alloc((size_t)NN * FD * 4);   // 12.8 MB
    float*    O    = (float*)alloc((size_t)NN * FD * 4);   // 12.8 MB

    const int B = 256;
    const int gN = (NN + B - 1) / B;
    const int gE = (NE + B - 1) / B;
    const int gemmBlocks   = 1024;   // 4096 waves
    const int gatherBlocks = 2048;   // 8192 waves, ~6 rows each

    // ---- CSR build (once, reused by both layers) ----
    k_cnt_init<<<gN, B, 0, stream>>>(cnt);
    k_cnt<<<gE, B, 0, stream>>>(dst, cnt);
    k_dis<<<gN, B, 0, stream>>>(cnt, dis);
    k_scan1<<<NBLK, SCAN_B, 0, stream>>>(cnt, rp, bsum);
    k_scan2<<<1, 256, 0, stream>>>(bsum);
    k_scan3<<<gN, B, 0, stream>>>(rp, bsum, cnt);
    k_fill<<<gE, B, 0, stream>>>(src, dst, rp, cnt, esrc);
    k_gmax_init<<<(NG * FD + B - 1) / B, B, 0, stream>>>(gmax);

    // ---- layer 1: H = x@W1 ; O = relu(gather(H) + b1) ----
    k_gemm64<<<gemmBlocks, B, 0, stream>>>(x, W1, H);
    k_gather<<<gatherBlocks, B, 0, stream>>>(rp, esrc, dis, H, b1, O, batch, gmax, 0);

    // ---- layer 2: H = O@W2 ; gmax = segmax(gather(H) + b2) ----
    k_gemm64<<<gemmBlocks, B, 0, stream>>>(O, W2, H);
    k_gather<<<gatherBlocks, B, 0, stream>>>(rp, esrc, dis, H, b2, O, batch, gmax, 1);

    // ---- head ----
    k_final<<<1, 128, 0, stream>>>(gmax, Wlin, blin, out);
}